// Round 6
// baseline (210.353 us; speedup 1.0000x reference)
//
#include <hip/hip_runtime.h>
#include <stdint.h>

typedef unsigned short u16;
typedef unsigned int u32;
typedef __attribute__((ext_vector_type(8))) short short8;
typedef __attribute__((ext_vector_type(4))) float f32x4;
typedef __attribute__((ext_vector_type(16))) float f32x16;

#define DEVI static __device__ __forceinline__

DEVI u16 f2bf(float f) {
  union { float f; u32 u; } v; v.f = f;
  u32 r = v.u + 0x7FFFu + ((v.u >> 16) & 1u);
  return (u16)(r >> 16);
}

DEVI u32 pack2bf(float lo, float hi) {
  return (u32)f2bf(lo) | ((u32)f2bf(hi) << 16);
}

// fast pack: round-half-up bf16 pair via v_perm_b32 (3 VALU ops / 2 elements)
DEVI u32 pack2bf_fast(float lo, float hi) {
  union { float f; u32 u; } a, b;
  a.f = lo; b.f = hi;
  return __builtin_amdgcn_perm(b.u + 0x8000u, a.u + 0x8000u, 0x07060302u);
}

DEVI void gload_lds16(const u16* g, u16* l) {
  __builtin_amdgcn_global_load_lds((const __attribute__((address_space(1))) void*)g,
                                   (__attribute__((address_space(3))) void*)l, 16, 0, 0);
}

// chunk swizzle: 16B chunk 'chunk' of row r lives at slot chunk^(r&7)^((r>>3)&3).
// returns u16 offset within the 64-u16 row.
DEVI int sw8(int chunk, int r) { return ((chunk ^ (r & 7) ^ ((r >> 3) & 3)) * 8); }

// ---------------- W [512,512] f32 -> W^T [512,512] bf16, 4 weights batched ----------------
__global__ __launch_bounds__(256) void tw4(const float* __restrict__ s0, const float* __restrict__ s1,
                                           const float* __restrict__ s2, const float* __restrict__ s3,
                                           u16* __restrict__ d0, u16* __restrict__ d1,
                                           u16* __restrict__ d2, u16* __restrict__ d3) {
  int z = blockIdx.z;
  const float* src = z == 0 ? s0 : z == 1 ? s1 : z == 2 ? s2 : s3;
  u16* dst = z == 0 ? d0 : z == 1 ? d1 : z == 2 ? d2 : d3;
  __shared__ float tile[32][33];
  int tx = threadIdx.x & 31, ty = threadIdx.x >> 5;
  int bx = blockIdx.x * 32, by = blockIdx.y * 32;
#pragma unroll
  for (int i = 0; i < 32; i += 8)
    tile[ty + i][tx] = src[(size_t)(by + ty + i) * 512 + bx + tx];
  __syncthreads();
#pragma unroll
  for (int i = 0; i < 32; i += 8)
    dst[(size_t)(bx + ty + i) * 512 + by + tx] = f2bf(tile[tx][ty + i]);
}

// ---------------- fused QKV GEMM: f32 A in, bf16 out; V written in VT layout ----------------
__global__ __launch_bounds__(256) void gemm_qkv(
    const float* __restrict__ A0, const float* __restrict__ A1, const float* __restrict__ A2,
    const u16* __restrict__ W0, const u16* __restrict__ W1, const u16* __restrict__ W2,
    const float* __restrict__ b0, const float* __restrict__ b1, const float* __restrict__ b2,
    u16* __restrict__ oq, u16* __restrict__ ok, u16* __restrict__ vt, float qscale) {
  const int z = blockIdx.z;
  const float* A = z == 0 ? A0 : z == 1 ? A1 : A2;
  const u16* WT = z == 0 ? W0 : z == 1 ? W1 : W2;
  const float* bias = z == 0 ? b0 : z == 1 ? b1 : b2;
  const float sc = z == 0 ? qscale : 1.0f;

  __shared__ __align__(16) u16 As[128 * 64];
  __shared__ __align__(16) u16 Bs[128 * 64];
  const int t = threadIdx.x;
  const int w = t >> 6, lane = t & 63, quad = lane >> 4, li = lane & 15;
  const int m0 = blockIdx.x * 128, n0 = blockIdx.y * 128;
  const int wm = (w >> 1) * 64, wn = (w & 1) * 64;

  f32x4 zv = {0.f, 0.f, 0.f, 0.f};
  f32x4 acc[4][4];
#pragma unroll
  for (int mi = 0; mi < 4; mi++)
#pragma unroll
    for (int ni = 0; ni < 4; ni++) acc[mi][ni] = zv;

  const int rA = t >> 3, cA = t & 7;
  for (int it = 0; it < 8; it++) {
    const int k0 = it * 64;
    // A: f32 global -> bf16 LDS (coalesced loads, swizzled ds_write_b128)
#pragma unroll
    for (int p = 0; p < 4; p++) {
      int r = p * 32 + rA;
      const float* ga = A + (size_t)(m0 + r) * 512 + k0 + cA * 8;
      float4 f0 = *(const float4*)ga;
      float4 f1 = *(const float4*)(ga + 4);
      uint4 pk;
      pk.x = pack2bf_fast(f0.x, f0.y);
      pk.y = pack2bf_fast(f0.z, f0.w);
      pk.z = pack2bf_fast(f1.x, f1.y);
      pk.w = pack2bf_fast(f1.z, f1.w);
      *(uint4*)&As[r * 64 + sw8(cA, r)] = pk;
    }
    // B: bf16 global -> LDS direct
#pragma unroll
    for (int p = 0; p < 4; p++) {
      int s = p * 256 + t;
      int r = s >> 3, c8 = s & 7;
      gload_lds16(WT + (size_t)(n0 + r) * 512 + k0 + sw8(c8, r), &Bs[(p * 256 + w * 64) * 8]);
    }
    __syncthreads();
#pragma unroll
    for (int ks = 0; ks < 2; ks++) {
      short8 af[4], bf[4];
#pragma unroll
      for (int mi = 0; mi < 4; mi++) {
        int r = wm + mi * 16 + li;
        af[mi] = *(const short8*)&As[r * 64 + sw8(ks * 4 + quad, r)];
      }
#pragma unroll
      for (int ni = 0; ni < 4; ni++) {
        int r = wn + ni * 16 + li;
        bf[ni] = *(const short8*)&Bs[r * 64 + sw8(ks * 4 + quad, r)];
      }
#pragma unroll
      for (int mi = 0; mi < 4; mi++)
#pragma unroll
        for (int ni = 0; ni < 4; ni++)
          acc[mi][ni] = __builtin_amdgcn_mfma_f32_16x16x32_bf16(af[mi], bf[ni], acc[mi][ni], 0, 0, 0);
    }
    __syncthreads();
  }

  float bv[4];
#pragma unroll
  for (int ni = 0; ni < 4; ni++) bv[ni] = bias[n0 + wn + ni * 16 + li];

  if (z < 2) {
    u16* out = z == 0 ? oq : ok;
#pragma unroll
    for (int mi = 0; mi < 4; mi++)
#pragma unroll
      for (int ni = 0; ni < 4; ni++)
#pragma unroll
        for (int r = 0; r < 4; r++) {
          int row = m0 + wm + mi * 16 + quad * 4 + r;
          int col = n0 + wn + ni * 16 + li;
          out[(size_t)row * 512 + col] = f2bf((acc[mi][ni][r] + bv[ni]) * sc);
        }
  } else {
    // V: write directly in VT [b, h, d, 2048] layout (4 consecutive l per lane = 8B store)
#pragma unroll
    for (int mi = 0; mi < 4; mi++)
#pragma unroll
      for (int ni = 0; ni < 4; ni++) {
        int col = n0 + wn + ni * 16 + li;
        int h = col >> 6, dd = col & 63;
        int row0 = m0 + wm + mi * 16 + quad * 4;
        int bb = row0 >> 11, l0 = row0 & 2047;
        uint2 dw;
        dw.x = pack2bf(acc[mi][ni][0] + bv[ni], acc[mi][ni][1] + bv[ni]);
        dw.y = pack2bf(acc[mi][ni][2] + bv[ni], acc[mi][ni][3] + bv[ni]);
        *(uint2*)&vt[((size_t)((bb * 8 + h) * 64 + dd)) * 2048 + l0] = dw;
      }
  }
}

// ---------------- GEMM 128x128, bf16 A (gload), f32 out (final projection) ----------------
__global__ __launch_bounds__(256) void gemm_out(const u16* __restrict__ A,
                                                const u16* __restrict__ WT,
                                                const float* __restrict__ bias,
                                                float* __restrict__ out) {
  __shared__ __align__(16) u16 As[128 * 64];
  __shared__ __align__(16) u16 Bs[128 * 64];
  const int t = threadIdx.x;
  const int w = t >> 6, lane = t & 63, quad = lane >> 4, li = lane & 15;
  const int m0 = blockIdx.x * 128, n0 = blockIdx.y * 128;
  const int wm = (w >> 1) * 64, wn = (w & 1) * 64;

  f32x4 zv = {0.f, 0.f, 0.f, 0.f};
  f32x4 acc[4][4];
#pragma unroll
  for (int mi = 0; mi < 4; mi++)
#pragma unroll
    for (int ni = 0; ni < 4; ni++) acc[mi][ni] = zv;

  for (int it = 0; it < 8; it++) {
    const int k0 = it * 64;
#pragma unroll
    for (int p = 0; p < 4; p++) {
      int s = p * 256 + t;
      int r = s >> 3, c8 = s & 7;
      gload_lds16(A + (size_t)(m0 + r) * 512 + k0 + sw8(c8, r), &As[(p * 256 + w * 64) * 8]);
      gload_lds16(WT + (size_t)(n0 + r) * 512 + k0 + sw8(c8, r), &Bs[(p * 256 + w * 64) * 8]);
    }
    __syncthreads();
#pragma unroll
    for (int ks = 0; ks < 2; ks++) {
      short8 af[4], bf[4];
#pragma unroll
      for (int mi = 0; mi < 4; mi++) {
        int r = wm + mi * 16 + li;
        af[mi] = *(const short8*)&As[r * 64 + sw8(ks * 4 + quad, r)];
      }
#pragma unroll
      for (int ni = 0; ni < 4; ni++) {
        int r = wn + ni * 16 + li;
        bf[ni] = *(const short8*)&Bs[r * 64 + sw8(ks * 4 + quad, r)];
      }
#pragma unroll
      for (int mi = 0; mi < 4; mi++)
#pragma unroll
        for (int ni = 0; ni < 4; ni++)
          acc[mi][ni] = __builtin_amdgcn_mfma_f32_16x16x32_bf16(af[mi], bf[ni], acc[mi][ni], 0, 0, 0);
    }
    __syncthreads();
  }

  float bv[4];
#pragma unroll
  for (int ni = 0; ni < 4; ni++) bv[ni] = bias[n0 + wn + ni * 16 + li];
#pragma unroll
  for (int mi = 0; mi < 4; mi++)
#pragma unroll
    for (int ni = 0; ni < 4; ni++)
#pragma unroll
      for (int r = 0; r < 4; r++) {
        int row = m0 + wm + mi * 16 + quad * 4 + r;
        int col = n0 + wn + ni * 16 + li;
        out[(size_t)row * 512 + col] = acc[mi][ni][r] + bv[ni];
      }
}

// ---------------- attention: 64 q per wave, K-split x2, partial O^T out ----------------
// grid (16 q-blocks of 128, h*2+s, b), block 128 = 2 waves x 64 q.
// S^T = K·Q^T (32x32x16; C col=q), O^T = V^T·P^T. No-max softmax (Q pre-scaled).
__global__ __launch_bounds__(128) void attn(const u16* __restrict__ Qp,
                                            const u16* __restrict__ Kp,
                                            const u16* __restrict__ VT,
                                            float* __restrict__ Op,
                                            float* __restrict__ Lb) {
  __shared__ __align__(16) u16 Ks[64 * 64];     // [kj][d]
  __shared__ __align__(16) u16 Vs[64 * 64];     // [d][kj]
  __shared__ __align__(16) u16 Ps[4][32 * 64];  // per (wave,unit) P buffers; Q staged here first
  const int t = threadIdx.x;
  const int w = t >> 6, lane = t & 63, qn = lane & 31, hi = lane >> 5;
  const int b = blockIdx.z, h = blockIdx.y >> 1, s = blockIdx.y & 1;
  const int q0 = blockIdx.x * 128;

  // stage Q tile (128 x 64) into the P region (each wave's Q rows lie in its own P buffers)
  u16* Qs = &Ps[0][0];
#pragma unroll
  for (int i = 0; i < 8; i++) {
    int si = i * 128 + t;
    int r = si >> 3, c8 = si & 7;
    gload_lds16(Qp + (size_t)(b * 2048 + q0 + r) * 512 + h * 64 + sw8(c8, r),
                &Qs[(i * 128 + w * 64) * 8]);
  }
  __syncthreads();
  short8 qf[2][4];
#pragma unroll
  for (int u = 0; u < 2; u++)
#pragma unroll
    for (int ks = 0; ks < 4; ks++) {
      int rq = w * 64 + u * 32 + qn;
      qf[u][ks] = *(const short8*)&Qs[rq * 64 + sw8(ks * 2 + hi, rq)];
    }

  f32x16 o[2][2];
#pragma unroll
  for (int u = 0; u < 2; u++)
#pragma unroll
    for (int dt = 0; dt < 2; dt++)
#pragma unroll
      for (int r = 0; r < 16; r++) o[u][dt][r] = 0.f;
  float lsum[2] = {0.f, 0.f};

  for (int kt = s * 16; kt < s * 16 + 16; kt++) {
    const int k0 = kt * 64;
#pragma unroll
    for (int i = 0; i < 4; i++) {
      int si = i * 128 + t;
      int r = si >> 3, c8 = si & 7;
      gload_lds16(Kp + (size_t)(b * 2048 + k0 + r) * 512 + h * 64 + sw8(c8, r),
                  &Ks[(i * 128 + w * 64) * 8]);
      gload_lds16(VT + ((size_t)((b * 8 + h) * 64 + r)) * 2048 + k0 + sw8(c8, r),
                  &Vs[(i * 128 + w * 64) * 8]);
    }
    __syncthreads();

#pragma unroll
    for (int u = 0; u < 2; u++) {
      // S^T = K·Q^T : 64 scores per lane for q-row (q0 + w*64 + u*32 + qn)
      f32x16 st[2];
#pragma unroll
      for (int kjt = 0; kjt < 2; kjt++) {
#pragma unroll
        for (int r = 0; r < 16; r++) st[kjt][r] = 0.f;
#pragma unroll
        for (int ks = 0; ks < 4; ks++) {
          int m = kjt * 32 + qn;
          short8 ka = *(const short8*)&Ks[m * 64 + sw8(ks * 2 + hi, m)];
          st[kjt] = __builtin_amdgcn_mfma_f32_32x32x16_bf16(ka, qf[u][ks], st[kjt], 0, 0, 0);
        }
      }

      // p = exp2(s), accumulate l, pack to per-(wave,unit) P buffer
      u16* pw = &Ps[w * 2 + u][0];
#pragma unroll
      for (int kjt = 0; kjt < 2; kjt++)
#pragma unroll
        for (int k8 = 0; k8 < 4; k8++) {
          float p0 = __builtin_amdgcn_exp2f(st[kjt][k8 * 4 + 0]);
          float p1 = __builtin_amdgcn_exp2f(st[kjt][k8 * 4 + 1]);
          float p2 = __builtin_amdgcn_exp2f(st[kjt][k8 * 4 + 2]);
          float p3 = __builtin_amdgcn_exp2f(st[kjt][k8 * 4 + 3]);
          lsum[u] += (p0 + p1) + (p2 + p3);
          uint2 dw;
          dw.x = pack2bf_fast(p0, p1);
          dw.y = pack2bf_fast(p2, p3);
          *(uint2*)&pw[qn * 64 + sw8(kjt * 4 + k8, qn) + hi * 4] = dw;
        }

      // O^T += V^T · P^T
      short8 pb[4];
#pragma unroll
      for (int ks = 0; ks < 4; ks++)
        pb[ks] = *(const short8*)&pw[qn * 64 + sw8(ks * 2 + hi, qn)];
#pragma unroll
      for (int dt = 0; dt < 2; dt++)
#pragma unroll
        for (int ks = 0; ks < 4; ks++) {
          int m = dt * 32 + qn;
          short8 va = *(const short8*)&Vs[m * 64 + sw8(ks * 2 + hi, m)];
          o[u][dt] = __builtin_amdgcn_mfma_f32_32x32x16_bf16(va, pb[ks], o[u][dt], 0, 0, 0);
        }
    }
    __syncthreads();
  }

  // epilogue: store partial O^T (f32, [d][q] layout, coalesced) + partial l
#pragma unroll
  for (int u = 0; u < 2; u++) {
    float l = lsum[u] + __shfl_xor(lsum[u], 32);
    int qg = q0 + w * 64 + u * 32 + qn;
    if (hi == 0) Lb[((size_t)((b * 8 + h) * 2 + s)) * 2048 + qg] = l;
#pragma unroll
    for (int dt = 0; dt < 2; dt++)
#pragma unroll
      for (int r = 0; r < 16; r++) {
        int d = dt * 32 + (r & 3) + 8 * (r >> 2) + 4 * hi;
        Op[((size_t)(((b * 8 + h) * 2 + s) * 64 + d)) * 2048 + qg] = o[u][dt][r];
      }
  }
}

// ---------------- combine K-splits, normalize, transpose [d][q] -> ctx [q][h*64+d] ----------------
__global__ __launch_bounds__(256) void reduce_o(const float* __restrict__ Op,
                                                const float* __restrict__ Lb,
                                                u16* __restrict__ ctx) {
  __shared__ float tile[64 * 65];  // [d][q], pitch 65
  const int t = threadIdx.x;
  const int b = blockIdx.z, h = blockIdx.y, q0 = blockIdx.x * 64;
  {
    int d = t >> 2, qc = (t & 3) * 16;
    const float* p0 = Op + ((size_t)(((b * 8 + h) * 2 + 0) * 64 + d)) * 2048 + q0 + qc;
    const float* p1 = Op + ((size_t)(((b * 8 + h) * 2 + 1) * 64 + d)) * 2048 + q0 + qc;
#pragma unroll
    for (int i = 0; i < 4; i++) {
      float4 a = *(const float4*)(p0 + i * 4);
      float4 c = *(const float4*)(p1 + i * 4);
      float4 v;
      v.x = a.x + c.x; v.y = a.y + c.y; v.z = a.z + c.z; v.w = a.w + c.w;
      *(float4*)&tile[d * 65 + qc + i * 4] = v;
    }
  }
  __syncthreads();
  {
    int q = t >> 2, dc = (t & 3) * 16;
    float l0 = Lb[((size_t)((b * 8 + h) * 2 + 0)) * 2048 + q0 + q];
    float l1 = Lb[((size_t)((b * 8 + h) * 2 + 1)) * 2048 + q0 + q];
    float inv = 1.0f / (l0 + l1);
    u32 pk[8];
#pragma unroll
    for (int i = 0; i < 8; i++) {
      float v0 = tile[(dc + i * 2) * 65 + q] * inv;      // O[d][q], read down a column
      float v1 = tile[(dc + i * 2 + 1) * 65 + q] * inv;
      pk[i] = pack2bf(v0, v1);
    }
    u16* dst = ctx + (size_t)(b * 2048 + q0 + q) * 512 + h * 64 + dc;
    *(uint4*)dst = *(uint4*)&pk[0];
    *(uint4*)(dst + 8) = *(uint4*)&pk[4];
  }
}

extern "C" void kernel_launch(void* const* d_in, const int* in_sizes, int n_in,
                              void* d_out, int out_size, void* d_ws, size_t ws_size,
                              hipStream_t stream) {
  const float* query = (const float*)d_in[0];
  const float* key_ = (const float*)d_in[1];
  const float* value = (const float*)d_in[2];
  const float* wq = (const float*)d_in[3];
  const float* bq = (const float*)d_in[4];
  const float* wk = (const float*)d_in[5];
  const float* bk = (const float*)d_in[6];
  const float* wv = (const float*)d_in[7];
  const float* bv = (const float*)d_in[8];
  const float* wo = (const float*)d_in[9];
  const float* bo = (const float*)d_in[10];

  char* ws = (char*)d_ws;
  const size_t SZ_W = (size_t)512 * 512 * 2;   // 512 KB
  const size_t SZ_X = (size_t)8192 * 512 * 2;  // 8 MB
  u16* wqT = (u16*)(ws);
  u16* wkT = (u16*)(ws + SZ_W);
  u16* wvT = (u16*)(ws + 2 * SZ_W);
  u16* woT = (u16*)(ws + 3 * SZ_W);
  u16* Qp = (u16*)(ws + 4 * SZ_W);
  u16* Kp = (u16*)(ws + 4 * SZ_W + SZ_X);
  u16* VTp = (u16*)(ws + 4 * SZ_W + 2 * SZ_X);
  float* Opb = (float*)(ws + 4 * SZ_W + 3 * SZ_X);                        // 32 MB (4·8·2·64 rows x 2048 f32)
  float* Lb = (float*)(ws + 4 * SZ_W + 3 * SZ_X + ((size_t)32 << 20));    // 512 KB
  u16* ctx = Qp;  // Qp dead after attn

  const float C1 = 0.125f * 1.44269504088896f;  // softmax scale * log2(e), folded into Q

  tw4<<<dim3(16, 16, 4), 256, 0, stream>>>(wq, wk, wv, wo, wqT, wkT, wvT, woT);
  gemm_qkv<<<dim3(64, 4, 3), 256, 0, stream>>>(query, key_, value, wqT, wkT, wvT,
                                               bq, bk, bv, Qp, Kp, VTp, C1);
  attn<<<dim3(16, 16, 4), 128, 0, stream>>>(Qp, Kp, VTp, Opb, Lb);
  reduce_o<<<dim3(32, 8, 4), 256, 0, stream>>>(Opb, Lb, ctx);
  gemm_out<<<dim3(64, 4), 256, 0, stream>>>(ctx, woT, bo, (float*)d_out);
}

// Round 7
// 199.340 us; speedup vs baseline: 1.0552x; 1.0552x over previous
//
#include <hip/hip_runtime.h>
#include <stdint.h>

typedef unsigned short u16;
typedef unsigned int u32;
typedef __attribute__((ext_vector_type(8))) short short8;
typedef __attribute__((ext_vector_type(4))) float f32x4;
typedef __attribute__((ext_vector_type(16))) float f32x16;

#define DEVI static __device__ __forceinline__

DEVI u16 f2bf(float f) {
  union { float f; u32 u; } v; v.f = f;
  u32 r = v.u + 0x7FFFu + ((v.u >> 16) & 1u);
  return (u16)(r >> 16);
}

DEVI u32 pack2bf(float lo, float hi) {
  return (u32)f2bf(lo) | ((u32)f2bf(hi) << 16);
}

// fast pack: round-half-up bf16 pair via v_perm_b32 (3 VALU ops / 2 elements)
DEVI u32 pack2bf_fast(float lo, float hi) {
  union { float f; u32 u; } a, b;
  a.f = lo; b.f = hi;
  return __builtin_amdgcn_perm(b.u + 0x8000u, a.u + 0x8000u, 0x07060302u);
}

DEVI void gload_lds16(const u16* g, u16* l) {
  __builtin_amdgcn_global_load_lds((const __attribute__((address_space(1))) void*)g,
                                   (__attribute__((address_space(3))) void*)l, 16, 0, 0);
}

// chunk swizzle: 16B chunk 'chunk' of row r lives at slot chunk^(r&7)^((r>>3)&3).
DEVI int sw8(int chunk, int r) { return ((chunk ^ (r & 7) ^ ((r >> 3) & 3)) * 8); }

// ---------------- W [512,512] f32 -> W^T [512,512] bf16, 4 weights batched ----------------
__global__ __launch_bounds__(256) void tw4(const float* __restrict__ s0, const float* __restrict__ s1,
                                           const float* __restrict__ s2, const float* __restrict__ s3,
                                           u16* __restrict__ d0, u16* __restrict__ d1,
                                           u16* __restrict__ d2, u16* __restrict__ d3) {
  int z = blockIdx.z;
  const float* src = z == 0 ? s0 : z == 1 ? s1 : z == 2 ? s2 : s3;
  u16* dst = z == 0 ? d0 : z == 1 ? d1 : z == 2 ? d2 : d3;
  __shared__ float tile[32][33];
  int tx = threadIdx.x & 31, ty = threadIdx.x >> 5;
  int bx = blockIdx.x * 32, by = blockIdx.y * 32;
#pragma unroll
  for (int i = 0; i < 32; i += 8)
    tile[ty + i][tx] = src[(size_t)(by + ty + i) * 512 + bx + tx];
  __syncthreads();
#pragma unroll
  for (int i = 0; i < 32; i += 8)
    dst[(size_t)(bx + ty + i) * 512 + by + tx] = f2bf(tile[tx][ty + i]);
}

// ---------------- fused QKV GEMM: f32 A in, bf16 out; V written in VT layout ----------------
__global__ __launch_bounds__(256) void gemm_qkv(
    const float* __restrict__ A0, const float* __restrict__ A1, const float* __restrict__ A2,
    const u16* __restrict__ W0, const u16* __restrict__ W1, const u16* __restrict__ W2,
    const float* __restrict__ b0, const float* __restrict__ b1, const float* __restrict__ b2,
    u16* __restrict__ oq, u16* __restrict__ ok, u16* __restrict__ vt, float qscale) {
  const int z = blockIdx.z;
  const float* A = z == 0 ? A0 : z == 1 ? A1 : A2;
  const u16* WT = z == 0 ? W0 : z == 1 ? W1 : W2;
  const float* bias = z == 0 ? b0 : z == 1 ? b1 : b2;
  const float sc = z == 0 ? qscale : 1.0f;

  __shared__ __align__(16) u16 As[128 * 64];
  __shared__ __align__(16) u16 Bs[128 * 64];
  const int t = threadIdx.x;
  const int w = t >> 6, lane = t & 63, quad = lane >> 4, li = lane & 15;
  const int m0 = blockIdx.x * 128, n0 = blockIdx.y * 128;
  const int wm = (w >> 1) * 64, wn = (w & 1) * 64;

  f32x4 zv = {0.f, 0.f, 0.f, 0.f};
  f32x4 acc[4][4];
#pragma unroll
  for (int mi = 0; mi < 4; mi++)
#pragma unroll
    for (int ni = 0; ni < 4; ni++) acc[mi][ni] = zv;

  const int rA = t >> 3, cA = t & 7;
  for (int it = 0; it < 8; it++) {
    const int k0 = it * 64;
#pragma unroll
    for (int p = 0; p < 4; p++) {
      int r = p * 32 + rA;
      const float* ga = A + (size_t)(m0 + r) * 512 + k0 + cA * 8;
      float4 f0 = *(const float4*)ga;
      float4 f1 = *(const float4*)(ga + 4);
      uint4 pk;
      pk.x = pack2bf_fast(f0.x, f0.y);
      pk.y = pack2bf_fast(f0.z, f0.w);
      pk.z = pack2bf_fast(f1.x, f1.y);
      pk.w = pack2bf_fast(f1.z, f1.w);
      *(uint4*)&As[r * 64 + sw8(cA, r)] = pk;
    }
#pragma unroll
    for (int p = 0; p < 4; p++) {
      int s = p * 256 + t;
      int r = s >> 3, c8 = s & 7;
      gload_lds16(WT + (size_t)(n0 + r) * 512 + k0 + sw8(c8, r), &Bs[(p * 256 + w * 64) * 8]);
    }
    __syncthreads();
#pragma unroll
    for (int ks = 0; ks < 2; ks++) {
      short8 af[4], bf[4];
#pragma unroll
      for (int mi = 0; mi < 4; mi++) {
        int r = wm + mi * 16 + li;
        af[mi] = *(const short8*)&As[r * 64 + sw8(ks * 4 + quad, r)];
      }
#pragma unroll
      for (int ni = 0; ni < 4; ni++) {
        int r = wn + ni * 16 + li;
        bf[ni] = *(const short8*)&Bs[r * 64 + sw8(ks * 4 + quad, r)];
      }
#pragma unroll
      for (int mi = 0; mi < 4; mi++)
#pragma unroll
        for (int ni = 0; ni < 4; ni++)
          acc[mi][ni] = __builtin_amdgcn_mfma_f32_16x16x32_bf16(af[mi], bf[ni], acc[mi][ni], 0, 0, 0);
    }
    __syncthreads();
  }

  float bv[4];
#pragma unroll
  for (int ni = 0; ni < 4; ni++) bv[ni] = bias[n0 + wn + ni * 16 + li];

  if (z < 2) {
    u16* out = z == 0 ? oq : ok;
#pragma unroll
    for (int mi = 0; mi < 4; mi++)
#pragma unroll
      for (int ni = 0; ni < 4; ni++)
#pragma unroll
        for (int r = 0; r < 4; r++) {
          int row = m0 + wm + mi * 16 + quad * 4 + r;
          int col = n0 + wn + ni * 16 + li;
          out[(size_t)row * 512 + col] = f2bf((acc[mi][ni][r] + bv[ni]) * sc);
        }
  } else {
    // V: write directly in VT [b, h, d, 2048] layout
#pragma unroll
    for (int mi = 0; mi < 4; mi++)
#pragma unroll
      for (int ni = 0; ni < 4; ni++) {
        int col = n0 + wn + ni * 16 + li;
        int h = col >> 6, dd = col & 63;
        int row0 = m0 + wm + mi * 16 + quad * 4;
        int bb = row0 >> 11, l0 = row0 & 2047;
        uint2 dw;
        dw.x = pack2bf(acc[mi][ni][0] + bv[ni], acc[mi][ni][1] + bv[ni]);
        dw.y = pack2bf(acc[mi][ni][2] + bv[ni], acc[mi][ni][3] + bv[ni]);
        *(uint2*)&vt[((size_t)((bb * 8 + h) * 64 + dd)) * 2048 + l0] = dw;
      }
  }
}

// ---------------- GEMM 128x64 tile, f32 out (final projection); 512 blocks = 2/CU ----------------
__global__ __launch_bounds__(256) void gemm_out(const u16* __restrict__ A,
                                                const u16* __restrict__ WT,
                                                const float* __restrict__ bias,
                                                float* __restrict__ out) {
  __shared__ __align__(16) u16 As[128 * 64];
  __shared__ __align__(16) u16 Bs[64 * 64];
  const int t = threadIdx.x;
  const int w = t >> 6, lane = t & 63, quad = lane >> 4, li = lane & 15;
  const int m0 = blockIdx.x * 128, n0 = blockIdx.y * 64;
  const int wm = (w >> 1) * 64, wn = (w & 1) * 32;

  f32x4 zv = {0.f, 0.f, 0.f, 0.f};
  f32x4 acc[4][2];
#pragma unroll
  for (int mi = 0; mi < 4; mi++)
#pragma unroll
    for (int ni = 0; ni < 2; ni++) acc[mi][ni] = zv;

  for (int it = 0; it < 8; it++) {
    const int k0 = it * 64;
#pragma unroll
    for (int p = 0; p < 4; p++) {
      int s = p * 256 + t;
      int r = s >> 3, c8 = s & 7;
      gload_lds16(A + (size_t)(m0 + r) * 512 + k0 + sw8(c8, r), &As[(p * 256 + w * 64) * 8]);
    }
#pragma unroll
    for (int p = 0; p < 2; p++) {
      int s = p * 256 + t;
      int r = s >> 3, c8 = s & 7;
      gload_lds16(WT + (size_t)(n0 + r) * 512 + k0 + sw8(c8, r), &Bs[(p * 256 + w * 64) * 8]);
    }
    __syncthreads();
#pragma unroll
    for (int ks = 0; ks < 2; ks++) {
      short8 af[4], bf[2];
#pragma unroll
      for (int mi = 0; mi < 4; mi++) {
        int r = wm + mi * 16 + li;
        af[mi] = *(const short8*)&As[r * 64 + sw8(ks * 4 + quad, r)];
      }
#pragma unroll
      for (int ni = 0; ni < 2; ni++) {
        int r = wn + ni * 16 + li;
        bf[ni] = *(const short8*)&Bs[r * 64 + sw8(ks * 4 + quad, r)];
      }
#pragma unroll
      for (int mi = 0; mi < 4; mi++)
#pragma unroll
        for (int ni = 0; ni < 2; ni++)
          acc[mi][ni] = __builtin_amdgcn_mfma_f32_16x16x32_bf16(af[mi], bf[ni], acc[mi][ni], 0, 0, 0);
    }
    __syncthreads();
  }

  float bv[2];
#pragma unroll
  for (int ni = 0; ni < 2; ni++) bv[ni] = bias[n0 + wn + ni * 16 + li];
#pragma unroll
  for (int mi = 0; mi < 4; mi++)
#pragma unroll
    for (int ni = 0; ni < 2; ni++)
#pragma unroll
      for (int r = 0; r < 4; r++) {
        int row = m0 + wm + mi * 16 + quad * 4 + r;
        int col = n0 + wn + ni * 16 + li;
        out[(size_t)row * 512 + col] = acc[mi][ni][r] + bv[ni];
      }
}

// ---------------- attention: 32 q per wave, 4 waves/block, K-split x2 ----------------
// grid (16 q-blocks of 128, h*2+s, b), block 256 = 4 waves x 32 q -> 16 waves/CU.
// S^T = K·Q^T (32x32x16; C col=q), O^T = V^T·P^T. No-max softmax (Q pre-scaled).
__global__ __launch_bounds__(256, 4) void attn(const u16* __restrict__ Qp,
                                               const u16* __restrict__ Kp,
                                               const u16* __restrict__ VT,
                                               float* __restrict__ Op,
                                               float* __restrict__ Lb) {
  __shared__ __align__(16) u16 Ks[64 * 64];     // [kj][d]
  __shared__ __align__(16) u16 Vs[64 * 64];     // [d][kj]
  __shared__ __align__(16) u16 Ps[4][32 * 64];  // per-wave P buffer
  const int t = threadIdx.x;
  const int w = t >> 6, lane = t & 63, qn = lane & 31, hi = lane >> 5;
  const int b = blockIdx.z, h = blockIdx.y >> 1, s = blockIdx.y & 1;
  const int q0 = blockIdx.x * 128;
  const int qrow = q0 + w * 32 + qn;

  // Q fragments direct from global (one-time): B[k=d][n=q]
  short8 qf[4];
  {
    const u16* qg = Qp + (size_t)(b * 2048 + qrow) * 512 + h * 64 + hi * 8;
#pragma unroll
    for (int ks = 0; ks < 4; ks++) qf[ks] = *(const short8*)(qg + ks * 16);
  }

  f32x16 o[2];
#pragma unroll
  for (int dt = 0; dt < 2; dt++)
#pragma unroll
    for (int r = 0; r < 16; r++) o[dt][r] = 0.f;
  float lsum = 0.f;

  u16* pw = &Ps[w][0];

  for (int kt = s * 16; kt < s * 16 + 16; kt++) {
    const int k0 = kt * 64;
#pragma unroll
    for (int i = 0; i < 2; i++) {
      int si = i * 256 + t;
      int r = si >> 3, c8 = si & 7;
      gload_lds16(Kp + (size_t)(b * 2048 + k0 + r) * 512 + h * 64 + sw8(c8, r),
                  &Ks[(i * 256 + w * 64) * 8]);
      gload_lds16(VT + ((size_t)((b * 8 + h) * 64 + r)) * 2048 + k0 + sw8(c8, r),
                  &Vs[(i * 256 + w * 64) * 8]);
    }
    __syncthreads();

    // S^T = K·Q^T : 32 scores per lane, all for q-row qrow
    f32x16 st[2];
#pragma unroll
    for (int kjt = 0; kjt < 2; kjt++) {
#pragma unroll
      for (int r = 0; r < 16; r++) st[kjt][r] = 0.f;
#pragma unroll
      for (int ks = 0; ks < 4; ks++) {
        int m = kjt * 32 + qn;
        short8 ka = *(const short8*)&Ks[m * 64 + sw8(ks * 2 + hi, m)];
        st[kjt] = __builtin_amdgcn_mfma_f32_32x32x16_bf16(ka, qf[ks], st[kjt], 0, 0, 0);
      }
    }

    // p = exp2(s), accumulate l, pack to per-wave P buffer [q][kj]
#pragma unroll
    for (int kjt = 0; kjt < 2; kjt++)
#pragma unroll
      for (int k8 = 0; k8 < 4; k8++) {
        float p0 = __builtin_amdgcn_exp2f(st[kjt][k8 * 4 + 0]);
        float p1 = __builtin_amdgcn_exp2f(st[kjt][k8 * 4 + 1]);
        float p2 = __builtin_amdgcn_exp2f(st[kjt][k8 * 4 + 2]);
        float p3 = __builtin_amdgcn_exp2f(st[kjt][k8 * 4 + 3]);
        lsum += (p0 + p1) + (p2 + p3);
        uint2 dw;
        dw.x = pack2bf_fast(p0, p1);
        dw.y = pack2bf_fast(p2, p3);
        *(uint2*)&pw[qn * 64 + sw8(kjt * 4 + k8, qn) + hi * 4] = dw;
      }

    // O^T += V^T · P^T (per-wave P buffer; no barrier needed)
    short8 pb[4];
#pragma unroll
    for (int ks = 0; ks < 4; ks++)
      pb[ks] = *(const short8*)&pw[qn * 64 + sw8(ks * 2 + hi, qn)];
#pragma unroll
    for (int dt = 0; dt < 2; dt++)
#pragma unroll
      for (int ks = 0; ks < 4; ks++) {
        int m = dt * 32 + qn;
        short8 va = *(const short8*)&Vs[m * 64 + sw8(ks * 2 + hi, m)];
        o[dt] = __builtin_amdgcn_mfma_f32_32x32x16_bf16(va, pb[ks], o[dt], 0, 0, 0);
      }
    __syncthreads();
  }

  // epilogue: store partial O^T (f32, [d][q] layout, coalesced) + partial l
  float l = lsum + __shfl_xor(lsum, 32);
  if (hi == 0) Lb[((size_t)((b * 8 + h) * 2 + s)) * 2048 + qrow] = l;
#pragma unroll
  for (int dt = 0; dt < 2; dt++)
#pragma unroll
    for (int r = 0; r < 16; r++) {
      int d = dt * 32 + (r & 3) + 8 * (r >> 2) + 4 * hi;
      Op[((size_t)(((b * 8 + h) * 2 + s) * 64 + d)) * 2048 + qrow] = o[dt][r];
    }
}

// ---------------- combine K-splits, normalize, transpose [d][q] -> ctx [q][h*64+d] ----------------
__global__ __launch_bounds__(256) void reduce_o(const float* __restrict__ Op,
                                                const float* __restrict__ Lb,
                                                u16* __restrict__ ctx) {
  __shared__ float tile[64 * 65];  // [d][q], pitch 65
  const int t = threadIdx.x;
  const int b = blockIdx.z, h = blockIdx.y, q0 = blockIdx.x * 64;
  {
    int d = t >> 2, qc = (t & 3) * 16;
    const float* p0 = Op + ((size_t)(((b * 8 + h) * 2 + 0) * 64 + d)) * 2048 + q0 + qc;
    const float* p1 = Op + ((size_t)(((b * 8 + h) * 2 + 1) * 64 + d)) * 2048 + q0 + qc;
#pragma unroll
    for (int i = 0; i < 4; i++) {
      float4 a = *(const float4*)(p0 + i * 4);
      float4 c = *(const float4*)(p1 + i * 4);
      float4 v;
      v.x = a.x + c.x; v.y = a.y + c.y; v.z = a.z + c.z; v.w = a.w + c.w;
      *(float4*)&tile[d * 65 + qc + i * 4] = v;
    }
  }
  __syncthreads();
  {
    int q = t >> 2, dc = (t & 3) * 16;
    float l0 = Lb[((size_t)((b * 8 + h) * 2 + 0)) * 2048 + q0 + q];
    float l1 = Lb[((size_t)((b * 8 + h) * 2 + 1)) * 2048 + q0 + q];
    float inv = 1.0f / (l0 + l1);
    u32 pk[8];
#pragma unroll
    for (int i = 0; i < 8; i++) {
      float v0 = tile[(dc + i * 2) * 65 + q] * inv;
      float v1 = tile[(dc + i * 2 + 1) * 65 + q] * inv;
      pk[i] = pack2bf(v0, v1);
    }
    u16* dst = ctx + (size_t)(b * 2048 + q0 + q) * 512 + h * 64 + dc;
    *(uint4*)dst = *(uint4*)&pk[0];
    *(uint4*)(dst + 8) = *(uint4*)&pk[4];
  }
}

extern "C" void kernel_launch(void* const* d_in, const int* in_sizes, int n_in,
                              void* d_out, int out_size, void* d_ws, size_t ws_size,
                              hipStream_t stream) {
  const float* query = (const float*)d_in[0];
  const float* key_ = (const float*)d_in[1];
  const float* value = (const float*)d_in[2];
  const float* wq = (const float*)d_in[3];
  const float* bq = (const float*)d_in[4];
  const float* wk = (const float*)d_in[5];
  const float* bk = (const float*)d_in[6];
  const float* wv = (const float*)d_in[7];
  const float* bv = (const float*)d_in[8];
  const float* wo = (const float*)d_in[9];
  const float* bo = (const float*)d_in[10];

  char* ws = (char*)d_ws;
  const size_t SZ_W = (size_t)512 * 512 * 2;   // 512 KB
  const size_t SZ_X = (size_t)8192 * 512 * 2;  // 8 MB
  u16* wqT = (u16*)(ws);
  u16* wkT = (u16*)(ws + SZ_W);
  u16* wvT = (u16*)(ws + 2 * SZ_W);
  u16* woT = (u16*)(ws + 3 * SZ_W);
  u16* Qp = (u16*)(ws + 4 * SZ_W);
  u16* Kp = (u16*)(ws + 4 * SZ_W + SZ_X);
  u16* VTp = (u16*)(ws + 4 * SZ_W + 2 * SZ_X);
  float* Opb = (float*)(ws + 4 * SZ_W + 3 * SZ_X);                        // 32 MB
  float* Lb = (float*)(ws + 4 * SZ_W + 3 * SZ_X + ((size_t)32 << 20));    // 512 KB
  u16* ctx = Qp;  // Qp dead after attn

  const float C1 = 0.125f * 1.44269504088896f;  // softmax scale * log2(e), folded into Q

  tw4<<<dim3(16, 16, 4), 256, 0, stream>>>(wq, wk, wv, wo, wqT, wkT, wvT, woT);
  gemm_qkv<<<dim3(64, 4, 3), 256, 0, stream>>>(query, key_, value, wqT, wkT, wvT,
                                               bq, bk, bv, Qp, Kp, VTp, C1);
  attn<<<dim3(16, 16, 4), 256, 0, stream>>>(Qp, Kp, VTp, Opb, Lb);
  reduce_o<<<dim3(32, 8, 4), 256, 0, stream>>>(Opb, Lb, ctx);
  gemm_out<<<dim3(64, 8), 256, 0, stream>>>(ctx, woT, bo, (float*)d_out);
}